// Round 6
// baseline (480.816 us; speedup 1.0000x reference)
//
#include <hip/hip_runtime.h>
#include <hip/hip_cooperative_groups.h>
#include <math.h>

namespace cg = cooperative_groups;

// GaussianKDE: out[b,l] = sum_n w[n] * exp(-||x[b,l]-data[n]||^2 / SIGMA)
// B=2, L=65536, D=2, N=16384, SIGMA=3.0
//
// R3: gridded fast Gauss transform: out = gather(sepconv_G(deposit(points)))
//     on a 256^2 grid, h=0.25, bicubic interp both sides. absmax 4.0 (passes).
// R4: memset -> kernel. No change (60us) => time is 5 launches + 4 graph gaps,
//     all kernels individually tiny (none reached the 38us top-5 cutoff).
// R5: fuse everything into ONE cooperative kernel with grid.sync() between
//     phases. Deposit spread to 1 atomic/thread. Conv taps fully unrolled so
//     exp2(-k^2*H2C2) constant-folds (no exp in hot loops). Fallback to the
//     known-good 5-kernel pipeline if cooperative launch fails under capture.

#define GRID_N   256
#define GRID_ORG (-32.0f)
#define GRID_INVH 4.0f          // 1/h, h = 0.25
#define CONV_R   32
#define H2C2     0.030056146685186739f  // h^2/(3*ln2): exp(-(kh)^2/3) = 2^(-k^2*H2C2)
#define KDE_C    0.48089834696298783f   // 1/(3*ln2)
#define NBLK     1024
#define NTHR     256

__device__ __forceinline__ float fast_exp2(float x) {
#if __has_builtin(__builtin_amdgcn_exp2f)
    return __builtin_amdgcn_exp2f(x);
#else
    float r;
    asm volatile("v_exp_f32 %0, %1" : "=v"(r) : "v"(x));
    return r;
#endif
}

// Cubic Lagrange weights for nodes {-1,0,1,2} at fractional t in [0,1).
__device__ __forceinline__ void cubw(float t, float w[4]) {
    float t2 = t * t;
    w[0] = -t * (t - 1.0f) * (t - 2.0f) * (1.0f / 6.0f);
    w[1] = (t2 - 1.0f) * (t - 2.0f) * 0.5f;
    w[2] = -t * (t + 1.0f) * (t - 2.0f) * 0.5f;
    w[3] = t * (t2 - 1.0f) * (1.0f / 6.0f);
}

__global__ __launch_bounds__(NTHR) void kde_fused(const float2* __restrict__ x,
                                                  const float* __restrict__ data,
                                                  const float* __restrict__ w,
                                                  float* __restrict__ A,     // grid, GRID_N^2
                                                  float* __restrict__ Bg,    // scratch, GRID_N^2
                                                  float* __restrict__ out,
                                                  int N, int M) {
    cg::grid_group grid = cg::this_grid();
    const int tid = blockIdx.x * NTHR + threadIdx.x;   // 0 .. 262143

    // ---- P0: zero A (16384 float4) ----
    if (tid < GRID_N * GRID_N / 4) {
        ((float4*)A)[tid] = make_float4(0.f, 0.f, 0.f, 0.f);
    }
    grid.sync();

    // ---- P1: deposit, exactly one atomicAdd per thread (N*16 == grid size) ----
    if (tid < (N << 4)) {
        int n  = tid >> 4;
        int dy = (tid >> 2) & 3;
        int dx = tid & 3;
        float d0 = data[2 * n], d1 = data[2 * n + 1], wn = w[n];
        float u = (d0 - GRID_ORG) * GRID_INVH;
        float v = (d1 - GRID_ORG) * GRID_INVH;
        float fu = floorf(u), fv = floorf(v);
        float tu = u - fu, tv = v - fv;
        int i0 = (int)fu - 1, j0 = (int)fv - 1;
        i0 = min(max(i0, 0), GRID_N - 4);   // safety only; |d| < 20
        j0 = min(max(j0, 0), GRID_N - 4);
        float wx[4], wy[4];
        cubw(tu, wx);
        cubw(tv, wy);
        atomicAdd(&A[(j0 + dy) * GRID_N + (i0 + dx)], wn * wy[dy] * wx[dx]);
    }
    grid.sync();

    // ---- P2: conv-x  A -> Bg (taps fully unrolled; exp2 constant-folds) ----
    if (tid < GRID_N * GRID_N) {
        int iy = tid >> 8, ix = tid & (GRID_N - 1);
        const float* row = A + iy * GRID_N;
        float s = 0.0f;
#pragma unroll
        for (int k = -CONV_R; k <= CONV_R; ++k) {
            int c = ix + k;
            if (c >= 0 && c < GRID_N) {
                s = fmaf(row[c], fast_exp2(-(float)(k * k) * H2C2), s);
            }
        }
        Bg[tid] = s;
    }
    grid.sync();

    // ---- P3: conv-y  Bg -> A (in place over the density grid; safe post-sync) ----
    if (tid < GRID_N * GRID_N) {
        int iy = tid >> 8, ix = tid & (GRID_N - 1);
        float s = 0.0f;
#pragma unroll
        for (int k = -CONV_R; k <= CONV_R; ++k) {
            int r = iy + k;
            if (r >= 0 && r < GRID_N) {
                s = fmaf(Bg[r * GRID_N + ix], fast_exp2(-(float)(k * k) * H2C2), s);
            }
        }
        A[tid] = s;
    }
    grid.sync();

    // ---- P4: gather (bicubic sample of A at each location) ----
    if (tid < M) {
        float2 xi = x[tid];
        float u = (xi.x - GRID_ORG) * GRID_INVH;
        float v = (xi.y - GRID_ORG) * GRID_INVH;
        float fu = floorf(u), fv = floorf(v);
        float tu = u - fu, tv = v - fv;
        int i0 = (int)fu - 1, j0 = (int)fv - 1;
        i0 = min(max(i0, 0), GRID_N - 4);
        j0 = min(max(j0, 0), GRID_N - 4);
        float wx[4], wy[4];
        cubw(tu, wx);
        cubw(tv, wy);
        float s = 0.0f;
#pragma unroll
        for (int dy = 0; dy < 4; ++dy) {
            const float* row = A + (j0 + dy) * GRID_N + i0;
            float r = wx[0] * row[0];
            r = fmaf(wx[1], row[1], r);
            r = fmaf(wx[2], row[2], r);
            r = fmaf(wx[3], row[3], r);
            s = fmaf(wy[dy], r, s);
        }
        out[tid] = s;
    }
}

// ------------------- fallback: R4 multi-kernel pipeline (known good) ---------
__global__ __launch_bounds__(256) void kde_zero(float4* __restrict__ A) {
    A[blockIdx.x * 256 + threadIdx.x] = make_float4(0.f, 0.f, 0.f, 0.f);
}

__global__ void kde_deposit(const float* __restrict__ data,
                            const float* __restrict__ w,
                            float* __restrict__ A, int N) {
    int n = blockIdx.x * blockDim.x + threadIdx.x;
    if (n >= N) return;
    float d0 = data[2 * n], d1 = data[2 * n + 1], wn = w[n];
    float u = (d0 - GRID_ORG) * GRID_INVH;
    float v = (d1 - GRID_ORG) * GRID_INVH;
    float fu = floorf(u), fv = floorf(v);
    float tu = u - fu, tv = v - fv;
    int i0 = (int)fu - 1, j0 = (int)fv - 1;
    i0 = min(max(i0, 0), GRID_N - 4);
    j0 = min(max(j0, 0), GRID_N - 4);
    float wx[4], wy[4];
    cubw(tu, wx);
    cubw(tv, wy);
#pragma unroll
    for (int dy = 0; dy < 4; ++dy) {
        float wwy = wn * wy[dy];
#pragma unroll
        for (int dx = 0; dx < 4; ++dx) {
            atomicAdd(&A[(j0 + dy) * GRID_N + (i0 + dx)], wwy * wx[dx]);
        }
    }
}

__global__ __launch_bounds__(256) void kde_convx(const float* __restrict__ A,
                                                 float* __restrict__ B) {
    int idx = blockIdx.x * blockDim.x + threadIdx.x;
    int iy = idx >> 8, ix = idx & (GRID_N - 1);
    const float* row = A + iy * GRID_N;
    float s = 0.0f;
#pragma unroll
    for (int k = -CONV_R; k <= CONV_R; ++k) {
        int c = ix + k;
        if (c >= 0 && c < GRID_N) {
            s = fmaf(row[c], fast_exp2(-(float)(k * k) * H2C2), s);
        }
    }
    B[idx] = s;
}

__global__ __launch_bounds__(256) void kde_convy(const float* __restrict__ B,
                                                 float* __restrict__ C) {
    int idx = blockIdx.x * blockDim.x + threadIdx.x;
    int iy = idx >> 8, ix = idx & (GRID_N - 1);
    float s = 0.0f;
#pragma unroll
    for (int k = -CONV_R; k <= CONV_R; ++k) {
        int r = iy + k;
        if (r >= 0 && r < GRID_N) {
            s = fmaf(B[r * GRID_N + ix], fast_exp2(-(float)(k * k) * H2C2), s);
        }
    }
    C[idx] = s;
}

__global__ __launch_bounds__(256) void kde_gather(const float2* __restrict__ x,
                                                  const float* __restrict__ C,
                                                  float* __restrict__ out, int M) {
    int i = blockIdx.x * blockDim.x + threadIdx.x;
    if (i >= M) return;
    float2 xi = x[i];
    float u = (xi.x - GRID_ORG) * GRID_INVH;
    float v = (xi.y - GRID_ORG) * GRID_INVH;
    float fu = floorf(u), fv = floorf(v);
    float tu = u - fu, tv = v - fv;
    int i0 = (int)fu - 1, j0 = (int)fv - 1;
    i0 = min(max(i0, 0), GRID_N - 4);
    j0 = min(max(j0, 0), GRID_N - 4);
    float wx[4], wy[4];
    cubw(tu, wx);
    cubw(tv, wy);
    float s = 0.0f;
#pragma unroll
    for (int dy = 0; dy < 4; ++dy) {
        const float* row = C + (j0 + dy) * GRID_N + i0;
        float r = wx[0] * row[0];
        r = fmaf(wx[1], row[1], r);
        r = fmaf(wx[2], row[2], r);
        r = fmaf(wx[3], row[3], r);
        s = fmaf(wy[dy], r, s);
    }
    out[i] = s;
}
// -----------------------------------------------------------------------------

extern "C" void kernel_launch(void* const* d_in, const int* in_sizes, int n_in,
                              void* d_out, int out_size, void* d_ws, size_t ws_size,
                              hipStream_t stream) {
    const float* data    = (const float*)d_in[1];   // (N, 2)    f32
    const float* weights = (const float*)d_in[2];   // (N,)      f32
    const float2* x2     = (const float2*)d_in[0];  // (B*L, 2)  f32
    float* out           = (float*)d_out;           // (B*L,)    f32

    int N     = in_sizes[2];          // 16384
    int n_loc = in_sizes[0] / 2;      // B*L = 131072

    float* A  = (float*)d_ws;                 // density / final grid
    float* Bg = A + GRID_N * GRID_N;          // conv-x intermediate

    void* args[] = {(void*)&x2, (void*)&data, (void*)&weights,
                    (void*)&A, (void*)&Bg, (void*)&out, (void*)&N, (void*)&n_loc};
    hipError_t err = hipLaunchCooperativeKernel((const void*)kde_fused,
                                                dim3(NBLK), dim3(NTHR),
                                                args, 0, stream);
    if (err != hipSuccess) {
        // Fallback: known-good multi-kernel pipeline.
        kde_zero<<<GRID_N * GRID_N / 4 / 256, 256, 0, stream>>>((float4*)A);
        kde_deposit<<<(N + 255) / 256, 256, 0, stream>>>(data, weights, A, N);
        kde_convx<<<GRID_N * GRID_N / 256, 256, 0, stream>>>(A, Bg);
        kde_convy<<<GRID_N * GRID_N / 256, 256, 0, stream>>>(Bg, A);
        kde_gather<<<(n_loc + 255) / 256, 256, 0, stream>>>(x2, A, out, n_loc);
    }
}

// Round 7
// 40.939 us; speedup vs baseline: 11.7447x; 11.7447x over previous
//
#include <hip/hip_runtime.h>
#include <math.h>

// GaussianKDE: out[b,l] = sum_n w[n] * exp(-||x[b,l]-data[n]||^2 / SIGMA)
// B=2, L=65536, D=2, N=16384, SIGMA=3.0
//
// Gridded fast Gauss transform (R3): out = gather(conv_y(conv_x(deposit)))
// on a 256^2 grid, h=0.25, bicubic interp both sides. absmax 4.0 (passes).
//
// R5 post-mortem: cg::grid.sync() = ~105us/sync on MI355X (1024-block
// arrive atomics + cross-XCD L2 wb/inv) -> 481us. Reverted.
// R6: cut dispatches 5 -> 3 without any grid-wide sync:
//   K1 kde_depx: block j owns grid ROW j in LDS (padded +-32). Scans all
//      N points (L2-resident), LDS-atomicAdd deposits hits, __syncthreads,
//      conv-x within LDS, writes Bg row j. Kills zero-kernel + global
//      atomics + one dispatch (row conv needs only its own row).
//   K2 kde_convy: column conv Bg -> C (coalesced, 17MB L2).
//   K3 kde_gather: bicubic sample of C at each location (unchanged).
// Launch overhead ~10us/dispatch dominates: predict ~40us total.

#define GRID_N   256
#define GRID_ORG (-32.0f)
#define GRID_INVH 4.0f          // 1/h, h = 0.25
#define CONV_R   32
#define H2C2     0.030056146685186739f  // h^2/(3*ln2): exp(-(kh)^2/3) = 2^(-k^2*H2C2)
#define PAD      32
#define ROWLEN   (GRID_N + 2 * PAD)     // 320 floats

__device__ __forceinline__ float fast_exp2(float x) {
#if __has_builtin(__builtin_amdgcn_exp2f)
    return __builtin_amdgcn_exp2f(x);
#else
    float r;
    asm volatile("v_exp_f32 %0, %1" : "=v"(r) : "v"(x));
    return r;
#endif
}

// Cubic Lagrange weights for nodes {-1,0,1,2} at fractional t in [0,1).
__device__ __forceinline__ void cubw(float t, float w[4]) {
    float t2 = t * t;
    w[0] = -t * (t - 1.0f) * (t - 2.0f) * (1.0f / 6.0f);
    w[1] = (t2 - 1.0f) * (t - 2.0f) * 0.5f;
    w[2] = -t * (t + 1.0f) * (t - 2.0f) * 0.5f;
    w[3] = t * (t2 - 1.0f) * (1.0f / 6.0f);
}

// K1: block j = one grid row. deposit (LDS atomics) + conv-x (LDS) -> Bg row.
__global__ __launch_bounds__(256) void kde_depx(const float2* __restrict__ data,
                                                const float* __restrict__ w,
                                                float* __restrict__ Bg, int N) {
    __shared__ float Arow[ROWLEN];
    const int j = blockIdx.x;

    for (int i = threadIdx.x; i < ROWLEN; i += 256) Arow[i] = 0.0f;
    __syncthreads();

    // scan all points; deposit those whose 4-row footprint covers row j
    for (int n = threadIdx.x; n < N; n += 256) {
        float2 d = data[n];
        float v  = (d.y - GRID_ORG) * GRID_INVH;
        float fv = floorf(v);
        int j0 = (int)fv - 1;
        j0 = min(max(j0, 0), GRID_N - 4);   // safety; |d| < 20
        int m = j - j0;
        if (m >= 0 && m <= 3) {
            float wn = w[n];
            float tv = v - fv;
            float wy[4];
            cubw(tv, wy);
            float wym = (m == 0) ? wy[0] : (m == 1) ? wy[1] : (m == 2) ? wy[2] : wy[3];
            float u  = (d.x - GRID_ORG) * GRID_INVH;
            float fu = floorf(u);
            int i0 = (int)fu - 1;
            i0 = min(max(i0, 0), GRID_N - 4);
            float tu = u - fu;
            float wx[4];
            cubw(tu, wx);
            float ww = wn * wym;
            atomicAdd(&Arow[PAD + i0 + 0], ww * wx[0]);
            atomicAdd(&Arow[PAD + i0 + 1], ww * wx[1]);
            atomicAdd(&Arow[PAD + i0 + 2], ww * wx[2]);
            atomicAdd(&Arow[PAD + i0 + 3], ww * wx[3]);
        }
    }
    __syncthreads();

    // conv-x within the row (pad guarantees in-bounds; stride-1 LDS = conflict-free)
    const int i = threadIdx.x;
    float s = 0.0f;
#pragma unroll
    for (int k = -CONV_R; k <= CONV_R; ++k) {
        s = fmaf(Arow[PAD + i + k], fast_exp2(-(float)(k * k) * H2C2), s);
    }
    Bg[j * GRID_N + i] = s;
}

// K2: conv-y  Bg -> C (coalesced across lanes)
__global__ __launch_bounds__(256) void kde_convy(const float* __restrict__ Bg,
                                                 float* __restrict__ C) {
    int idx = blockIdx.x * 256 + threadIdx.x;   // 65536 cells
    int iy = idx >> 8, ix = idx & (GRID_N - 1);
    float s = 0.0f;
#pragma unroll
    for (int k = -CONV_R; k <= CONV_R; ++k) {
        int r = iy + k;
        if (r >= 0 && r < GRID_N) {
            s = fmaf(Bg[r * GRID_N + ix], fast_exp2(-(float)(k * k) * H2C2), s);
        }
    }
    C[idx] = s;
}

// K3: bicubic gather of C at each location
__global__ __launch_bounds__(256) void kde_gather(const float2* __restrict__ x,
                                                  const float* __restrict__ C,
                                                  float* __restrict__ out, int M) {
    int i = blockIdx.x * 256 + threadIdx.x;
    if (i >= M) return;
    float2 xi = x[i];
    float u = (xi.x - GRID_ORG) * GRID_INVH;
    float v = (xi.y - GRID_ORG) * GRID_INVH;
    float fu = floorf(u), fv = floorf(v);
    float tu = u - fu, tv = v - fv;
    int i0 = (int)fu - 1, j0 = (int)fv - 1;
    i0 = min(max(i0, 0), GRID_N - 4);
    j0 = min(max(j0, 0), GRID_N - 4);
    float wx[4], wy[4];
    cubw(tu, wx);
    cubw(tv, wy);
    float s = 0.0f;
#pragma unroll
    for (int dy = 0; dy < 4; ++dy) {
        const float* row = C + (j0 + dy) * GRID_N + i0;
        float r = wx[0] * row[0];
        r = fmaf(wx[1], row[1], r);
        r = fmaf(wx[2], row[2], r);
        r = fmaf(wx[3], row[3], r);
        s = fmaf(wy[dy], r, s);
    }
    out[i] = s;
}

extern "C" void kernel_launch(void* const* d_in, const int* in_sizes, int n_in,
                              void* d_out, int out_size, void* d_ws, size_t ws_size,
                              hipStream_t stream) {
    const float2* x      = (const float2*)d_in[0];  // (B*L, 2) f32
    const float* data    = (const float*)d_in[1];   // (N, 2)   f32
    const float* weights = (const float*)d_in[2];   // (N,)     f32
    float* out           = (float*)d_out;           // (B*L,)   f32

    const int N     = in_sizes[2];        // 16384
    const int n_loc = in_sizes[0] / 2;    // 131072

    float* Bg = (float*)d_ws;                     // conv-x result, 256KB
    float* C  = Bg + GRID_N * GRID_N;             // conv-y result, 256KB

    kde_depx<<<GRID_N, 256, 0, stream>>>((const float2*)data, weights, Bg, N);
    kde_convy<<<GRID_N * GRID_N / 256, 256, 0, stream>>>(Bg, C);
    kde_gather<<<(n_loc + 255) / 256, 256, 0, stream>>>(x, C, out, n_loc);
}